// Round 2
// baseline (329.358 us; speedup 1.0000x reference)
//
#include <hip/hip_runtime.h>
#include <hip/hip_bf16.h>
#include <stdint.h>

// out = (QK^T/sqrt(d))V = Q @ (K^T V)/sqrt(d)   (no softmax in ref)
// K^T V = Wk G Wv^T + (Wk s) bv^T + bk (Wv s)^T + L bk bv^T,  G = x^T x, s = colsum(x)
// out = x (Wq^T M) + 1 (bq^T M),  M = K^T V / sqrt(d)
// Working set ~47.7 MB (ws overflow was round-1's post-timing failure).

#define BM 128
#define BN 128
#define BK 32

typedef __attribute__((ext_vector_type(8))) short short8;
typedef __attribute__((ext_vector_type(4))) float f32x4;
typedef __attribute__((address_space(3))) void lds_void;
typedef const __attribute__((address_space(1))) void gmem_void;

__device__ __forceinline__ unsigned short f2bf(float f) {
  union { float f; unsigned u; } v; v.f = f;
  unsigned r = v.u + 0x7fff + ((v.u >> 16) & 1);   // RNE
  return (unsigned short)(r >> 16);
}
__device__ __forceinline__ float bf2f(unsigned short u) {
  union { unsigned u; float f; } v; v.u = ((unsigned)u) << 16; return v.f;
}

__global__ __launch_bounds__(256) void cast_f32_bf16(
    const float* __restrict__ in, unsigned short* __restrict__ out, int n) {
  int i = (blockIdx.x * blockDim.x + threadIdx.x) * 8;
  if (i >= n) return;
  float4 v0 = *(const float4*)(in + i);
  float4 v1 = *(const float4*)(in + i + 4);
  unsigned short o[8];
  o[0] = f2bf(v0.x); o[1] = f2bf(v0.y); o[2] = f2bf(v0.z); o[3] = f2bf(v0.w);
  o[4] = f2bf(v1.x); o[5] = f2bf(v1.y); o[6] = f2bf(v1.z); o[7] = f2bf(v1.w);
  typedef __attribute__((ext_vector_type(8))) unsigned short ushort8;
  *(ushort8*)(out + i) = *(ushort8*)o;
}

// out[c*R + r] = bf16(in[r*C + c]);  R=C=768, grid (C/32, R/32), block 256
__global__ __launch_bounds__(256) void transpose_cast(
    const float* __restrict__ in, unsigned short* __restrict__ out, int R, int C) {
  __shared__ float tile[32][33];
  int r0 = blockIdx.y * 32, c0 = blockIdx.x * 32;
  int tx = threadIdx.x & 31, ty = threadIdx.x >> 5;   // ty 0..7
  for (int i = ty; i < 32; i += 8) tile[i][tx] = in[(long)(r0 + i) * C + c0 + tx];
  __syncthreads();
  for (int i = ty; i < 32; i += 8) out[(long)(c0 + i) * R + r0 + tx] = f2bf(tile[tx][i]);
}

// s[z*768 + d] = sum_l x[z,l,d];  grid (6, 8), block 256
__global__ __launch_bounds__(256) void colsum(const float* __restrict__ x,
                                              float* __restrict__ s) {
  int z = blockIdx.y;
  int d = blockIdx.x * 128 + (threadIdx.x & 127);
  int half = threadIdx.x >> 7;
  const float* p = x + ((long)z * 2048 + half * 1024) * 768 + d;
  float acc = 0.f;
  for (int l = 0; l < 1024; ++l) acc += p[(long)l * 768];
  __shared__ float red[256];
  red[threadIdx.x] = acc;
  __syncthreads();
  if (half == 0) s[z * 768 + d] = red[threadIdx.x] + red[threadIdx.x + 128];
}

// out[z*768 + m] = sum_k A[z*a_bs + m*768 + k] * v[z*v_bs + k]
// grid (24, 8), block 256: 4 waves x 8 rows each
template<int ABF16>
__global__ __launch_bounds__(256) void gemv768(const void* __restrict__ Av,
                                               const float* __restrict__ v,
                                               float* __restrict__ out,
                                               long a_bs, long v_bs) {
  int z = blockIdx.y;
  int wid = threadIdx.x >> 6, lane = threadIdx.x & 63;
  for (int mi = 0; mi < 8; ++mi) {
    int m = blockIdx.x * 32 + wid * 8 + mi;
    float acc = 0.f;
    for (int k = lane; k < 768; k += 64) {
      float a = ABF16 ? bf2f(((const unsigned short*)Av)[z * a_bs + (long)m * 768 + k])
                      : ((const float*)Av)[z * a_bs + (long)m * 768 + k];
      acc += a * v[z * v_bs + k];
    }
#pragma unroll
    for (int off = 32; off; off >>= 1) acc += __shfl_down(acc, off);
    if (lane == 0) out[z * 768 + m] = acc;
  }
}

// G[z][i,j] = sum_l xb[z*2048+l, i] * xb[z*2048+l, j]  (bf16 in/out, f32 acc)
// grid (6, 6, 8), block 256
#define GS 40   // padded LDS row stride (elements)
__global__ __launch_bounds__(256, 2) void syrk_g(const unsigned short* __restrict__ xb,
                                                 unsigned short* __restrict__ G) {
  __shared__ unsigned short At[128 * GS];
  __shared__ unsigned short Bt[128 * GS];
  const int tid = threadIdx.x;
  const int wid = tid >> 6, lane = tid & 63;
  const int z = blockIdx.z;
  const int i0 = blockIdx.y * 128, j0 = blockIdx.x * 128;

  f32x4 acc[4][4];
#pragma unroll
  for (int r = 0; r < 4; ++r)
#pragma unroll
    for (int c = 0; c < 4; ++c) acc[r][c] = (f32x4){0.f, 0.f, 0.f, 0.f};

  const int lp = (tid & 15) * 2;        // even l within 32-row K-tile
  const int d8 = (tid >> 4) * 8;        // 0..120
  const int fr = lane & 15;
  const int kf = (lane >> 4) * 8;

  const unsigned short* xz = xb + (long)z * 2048 * 768;

  for (int l0 = 0; l0 < 2048; l0 += 32) {
    short8 a0 = *(const short8*)(xz + (long)(l0 + lp) * 768 + i0 + d8);
    short8 a1 = *(const short8*)(xz + (long)(l0 + lp + 1) * 768 + i0 + d8);
    short8 b0 = *(const short8*)(xz + (long)(l0 + lp) * 768 + j0 + d8);
    short8 b1 = *(const short8*)(xz + (long)(l0 + lp + 1) * 768 + j0 + d8);
#pragma unroll
    for (int e = 0; e < 8; ++e) {
      ushort2 pa; pa.x = (unsigned short)a0[e]; pa.y = (unsigned short)a1[e];
      ushort2 pb; pb.x = (unsigned short)b0[e]; pb.y = (unsigned short)b1[e];
      *(ushort2*)&At[(d8 + e) * GS + lp] = pa;
      *(ushort2*)&Bt[(d8 + e) * GS + lp] = pb;
    }
    __syncthreads();

    short8 af[4], bfr[4];
#pragma unroll
    for (int r = 0; r < 4; ++r)
      af[r] = *(const short8*)(At + ((wid >> 1) * 64 + r * 16 + fr) * GS + kf);
#pragma unroll
    for (int c = 0; c < 4; ++c)
      bfr[c] = *(const short8*)(Bt + ((wid & 1) * 64 + c * 16 + fr) * GS + kf);
#pragma unroll
    for (int r = 0; r < 4; ++r)
#pragma unroll
      for (int c = 0; c < 4; ++c)
        acc[r][c] = __builtin_amdgcn_mfma_f32_16x16x32_bf16(af[r], bfr[c], acc[r][c], 0, 0, 0);
    __syncthreads();
  }

  const int wr = (wid >> 1) * 64, wc = (wid & 1) * 64;
  const int cr0 = (lane >> 4) * 4, cc = lane & 15;
  unsigned short* Gz = G + (long)z * 768 * 768;
#pragma unroll
  for (int r = 0; r < 4; ++r)
#pragma unroll
    for (int c = 0; c < 4; ++c)
#pragma unroll
      for (int j = 0; j < 4; ++j) {
        int row = i0 + wr + r * 16 + cr0 + j;
        int col = j0 + wc + c * 16 + cc;
        Gz[(long)row * 768 + col] = f2bf(acc[r][c][j]);
      }
}

// C[m,n] = scale*sum_k A[m,k]*B[n,k] (+bias terms)
// BIAS_MODE: 0 none; 1: += bias[bz*bias_bs + col];
//            3: v = scale*(acc + bias[row]*(b2[bz*768+col] + 2048*b4[col]) + b3[bz*768+row]*b4[col])
template<int BIAS_MODE, int OUT_BF16>
__global__ __launch_bounds__(256, 2)
void gemm_bt(const unsigned short* __restrict__ A,
             const unsigned short* __restrict__ B,
             const float* __restrict__ bias, const float* __restrict__ b2,
             const float* __restrict__ b3, const float* __restrict__ b4,
             void* __restrict__ Cv,
             int K, int lda, int ldb, int ldc,
             long a_bs, long b_bs, long c_bs, long bias_bs, float scale)
{
  __shared__ unsigned short As[BM * BK];
  __shared__ unsigned short Bs[BN * BK];

  const int tid  = threadIdx.x;
  const int wid  = tid >> 6;
  const int lane = tid & 63;
  const int bz   = blockIdx.z;
  const long bm  = (long)blockIdx.y * BM;
  const long bn  = (long)blockIdx.x * BN;

  const unsigned short* Ab = A + (long)bz * a_bs;
  const unsigned short* Bb = B + (long)bz * b_bs;

  f32x4 acc[4][4];
#pragma unroll
  for (int r = 0; r < 4; ++r)
#pragma unroll
    for (int c = 0; c < 4; ++c) acc[r][c] = (f32x4){0.f, 0.f, 0.f, 0.f};

  const int stg_row = lane >> 2;
  const int stg_k   = (lane & 3) * 8;
  const int fr = lane & 15;
  const int kf = (lane >> 4) * 8;

  for (int k0 = 0; k0 < K; k0 += BK) {
#pragma unroll
    for (int i = 0; i < 2; ++i) {
      const int g = wid * 2 + i;
      const unsigned short* ga = Ab + (bm + g * 16 + stg_row) * (long)lda + k0 + stg_k;
      __builtin_amdgcn_global_load_lds((gmem_void*)ga, (lds_void*)(As + g * 16 * BK), 16, 0, 0);
      const unsigned short* gb = Bb + (bn + g * 16 + stg_row) * (long)ldb + k0 + stg_k;
      __builtin_amdgcn_global_load_lds((gmem_void*)gb, (lds_void*)(Bs + g * 16 * BK), 16, 0, 0);
    }
    __syncthreads();

    short8 af[4], bfr[4];
#pragma unroll
    for (int r = 0; r < 4; ++r)
      af[r] = *(const short8*)(As + ((wid >> 1) * 64 + r * 16 + fr) * BK + kf);
#pragma unroll
    for (int c = 0; c < 4; ++c)
      bfr[c] = *(const short8*)(Bs + ((wid & 1) * 64 + c * 16 + fr) * BK + kf);
#pragma unroll
    for (int r = 0; r < 4; ++r)
#pragma unroll
      for (int c = 0; c < 4; ++c)
        acc[r][c] = __builtin_amdgcn_mfma_f32_16x16x32_bf16(af[r], bfr[c], acc[r][c], 0, 0, 0);
    __syncthreads();
  }

  const int wr  = (wid >> 1) * 64;
  const int wc  = (wid & 1) * 64;
  const int cr0 = (lane >> 4) * 4;
  const int cc  = lane & 15;

#pragma unroll
  for (int r = 0; r < 4; ++r)
#pragma unroll
    for (int c = 0; c < 4; ++c)
#pragma unroll
      for (int j = 0; j < 4; ++j) {
        long row = bm + wr + r * 16 + cr0 + j;
        long col = bn + wc + c * 16 + cc;
        float v = acc[r][c][j] * scale;
        if (BIAS_MODE == 1) v += bias[bz * bias_bs + col];
        else if (BIAS_MODE == 3)
          v += scale * (bias[row] * (b2[bz * 768 + col] + 2048.0f * b4[col])
                        + b3[bz * 768 + row] * b4[col]);
        long off = (long)bz * c_bs + row * (long)ldc + col;
        if (OUT_BF16) ((unsigned short*)Cv)[off] = f2bf(v);
        else          ((float*)Cv)[off] = v;
      }
}

extern "C" void kernel_launch(void* const* d_in, const int* in_sizes, int n_in,
                              void* d_out, int out_size, void* d_ws, size_t ws_size,
                              hipStream_t stream) {
  const float* x  = (const float*)d_in[0];
  const float* Wq = (const float*)d_in[1];
  const float* bq = (const float*)d_in[2];
  const float* Wk = (const float*)d_in[3];
  const float* bk = (const float*)d_in[4];
  const float* Wv = (const float*)d_in[5];
  const float* bv = (const float*)d_in[6];
  float* out = (float*)d_out;

  const int Bsz = 8, L = 2048, D = 768;
  const int BL = Bsz * L;                  // 16384
  const long xN = (long)BL * D;            // 12,582,912
  const long wN = (long)D * D;             // 589,824
  const long D2 = wN;

  char* ws = (char*)d_ws;
  unsigned short* xb   = (unsigned short*)ws; ws += xN * 2;            // 25.2 MB
  unsigned short* wkb  = (unsigned short*)ws; ws += wN * 2;            // 1.2 MB
  unsigned short* wvb  = (unsigned short*)ws; ws += wN * 2;
  unsigned short* wqtb = (unsigned short*)ws; ws += wN * 2;            // Wq^T
  unsigned short* regA = (unsigned short*)ws; ws += (long)Bsz * D2 * 2; // 9.4 MB (G, then Mt)
  unsigned short* regB = (unsigned short*)ws; ws += (long)Bsz * D2 * 2; // 9.4 MB (N, then Pt)
  float* sv = (float*)ws; ws += (long)Bsz * D * 4;
  float* uv = (float*)ws; ws += (long)Bsz * D * 4;
  float* wv = (float*)ws; ws += (long)Bsz * D * 4;
  float* rv = (float*)ws; ws += (long)Bsz * D * 4;   // total ~47.7 MB

  const float inv_sqrt_d = 0.036084391824351615f;  // 1/sqrt(768)
  dim3 blk(256);

  colsum<<<dim3(6, 8), blk, 0, stream>>>(x, sv);
  cast_f32_bf16<<<(int)(xN / 8 / 256), blk, 0, stream>>>(x,  xb,  (int)xN);
  cast_f32_bf16<<<(int)(wN / 8 / 256), blk, 0, stream>>>(Wk, wkb, (int)wN);
  cast_f32_bf16<<<(int)(wN / 8 / 256), blk, 0, stream>>>(Wv, wvb, (int)wN);
  transpose_cast<<<dim3(24, 24), blk, 0, stream>>>(Wq, wqtb, D, D);

  // u = Wk s, w = Wv s (exact f32)
  gemv768<0><<<dim3(24, 8), blk, 0, stream>>>(Wk, sv, uv, 0, (long)D);
  gemv768<0><<<dim3(24, 8), blk, 0, stream>>>(Wv, sv, wv, 0, (long)D);

  // G = x^T x per batch -> regA (bf16)
  syrk_g<<<dim3(6, 6, 8), blk, 0, stream>>>(xb, regA);

  // N = Wv * G (G symmetric -> use G as B)  -> regB
  gemm_bt<0, 1><<<dim3(6, 6, 8), blk, 0, stream>>>(
      wvb, regA, nullptr, nullptr, nullptr, nullptr, regB,
      D, D, D, D, 0, D2, D2, 0, 1.0f);

  // Mt = (N * Wk^T + rank-1) * inv_sqrt_d  -> regA   (Mt = M^T = (K^T V)^T/sqrt(d))
  gemm_bt<3, 1><<<dim3(6, 6, 8), blk, 0, stream>>>(
      regB, wkb, bv, uv, wv, bk, regA,
      D, D, D, D, D2, 0, D2, 0, inv_sqrt_d);

  // r[z][o] = sum_h Mt[z][o,h] * bq[h]
  gemv768<1><<<dim3(24, 8), blk, 0, stream>>>(regA, bq, rv, D2, 0);

  // Pt = Mt * Wqt^T  -> regB    (Pt[o,d] = P[d,o], P = Wq^T M)
  gemm_bt<0, 1><<<dim3(6, 6, 8), blk, 0, stream>>>(
      regA, wqtb, nullptr, nullptr, nullptr, nullptr, regB,
      D, D, D, D, D2, 0, D2, 0, 1.0f);

  // out[z][l,o] = sum_d xb[z,l,d] * Pt[z][o,d] + r[z][o]
  gemm_bt<1, 0><<<dim3(6, 16, 8), blk, 0, stream>>>(
      xb, regB, rv, nullptr, nullptr, nullptr, out,
      D, D, D, D, (long)L * D, D2, (long)L * D, (long)D, 1.0f);

  (void)in_sizes; (void)n_in; (void)out_size; (void)ws_size;
}

// Round 3
// 266.646 us; speedup vs baseline: 1.2352x; 1.2352x over previous
//
#include <hip/hip_runtime.h>
#include <hip/hip_bf16.h>
#include <stdint.h>

// out = (QK^T/sqrt(d))V = Q @ (K^T V)/sqrt(d)   (no softmax in ref)
// K^T V = Wk G Wv^T + (Wk s) bv^T + bk (Wv s)^T + L bk bv^T,  G = x^T x, s = colsum(x)
// out = x (Wq^T M) + 1 (bq^T M),  M = K^T V / sqrt(d)
// ws kept at ~47.7 MB (round-1 overflow lesson): xt and xb share one buffer,
// x is re-cast after the G-GEMM consumes xt.

#define BM 128
#define BN 128
#define BK 32

typedef __attribute__((ext_vector_type(8))) short short8;
typedef __attribute__((ext_vector_type(4))) float f32x4;
typedef __attribute__((address_space(3))) void lds_void;
typedef const __attribute__((address_space(1))) void gmem_void;

__device__ __forceinline__ unsigned short f2bf(float f) {
  union { float f; unsigned u; } v; v.f = f;
  unsigned r = v.u + 0x7fff + ((v.u >> 16) & 1);   // RNE
  return (unsigned short)(r >> 16);
}
__device__ __forceinline__ float bf2f(unsigned short u) {
  union { unsigned u; float f; } v; v.u = ((unsigned)u) << 16; return v.f;
}

__global__ __launch_bounds__(256) void cast_f32_bf16(
    const float* __restrict__ in, unsigned short* __restrict__ out, int n) {
  int i = (blockIdx.x * blockDim.x + threadIdx.x) * 8;
  if (i >= n) return;
  float4 v0 = *(const float4*)(in + i);
  float4 v1 = *(const float4*)(in + i + 4);
  unsigned short o[8];
  o[0] = f2bf(v0.x); o[1] = f2bf(v0.y); o[2] = f2bf(v0.z); o[3] = f2bf(v0.w);
  o[4] = f2bf(v1.x); o[5] = f2bf(v1.y); o[6] = f2bf(v1.z); o[7] = f2bf(v1.w);
  typedef __attribute__((ext_vector_type(8))) unsigned short ushort8;
  *(ushort8*)(out + i) = *(ushort8*)o;
}

// out[c*R + r] = bf16(in[r*C + c]);  R=C=768 (for Wq^T)
__global__ __launch_bounds__(256) void transpose_cast(
    const float* __restrict__ in, unsigned short* __restrict__ out, int R, int C) {
  __shared__ float tile[32][33];
  int r0 = blockIdx.y * 32, c0 = blockIdx.x * 32;
  int tx = threadIdx.x & 31, ty = threadIdx.x >> 5;
  for (int i = ty; i < 32; i += 8) tile[i][tx] = in[(long)(r0 + i) * C + c0 + tx];
  __syncthreads();
  for (int i = ty; i < 32; i += 8) out[(long)(c0 + i) * R + r0 + tx] = f2bf(tile[tx][i]);
}

// xt[z][d][l] = bf16(x[z][l][d]); tiles 64 l x 32 d. grid (32, 24, 8), block 256
__global__ __launch_bounds__(256) void transpose_x(
    const float* __restrict__ x, unsigned short* __restrict__ xt) {
  __shared__ float tile[64][33];
  const int z = blockIdx.z;
  const int l0 = blockIdx.x * 64, d0 = blockIdx.y * 32;
  const int tx = threadIdx.x & 31, ty = threadIdx.x >> 5;   // ty 0..7
  const float* xz = x + ((long)z * 2048 + l0) * 768 + d0;
#pragma unroll
  for (int i = 0; i < 8; ++i)
    tile[i * 8 + ty][tx] = xz[(long)(i * 8 + ty) * 768 + tx];
  __syncthreads();
  unsigned short* xtz = xt + ((long)z * 768 + d0) * 2048 + l0;
#pragma unroll
  for (int i = 0; i < 4; ++i) {
    int d = i * 8 + ty;
    ushort2 o;
    o.x = f2bf(tile[2 * tx][d]);
    o.y = f2bf(tile[2 * tx + 1][d]);
    *(ushort2*)(xtz + (long)d * 2048 + 2 * tx) = o;
  }
}

// sv[row] = sum_l xt[row][l], row = z*768+d. grid 1536, block 256 (4 rows/block)
__global__ __launch_bounds__(256) void colsum_t(
    const unsigned short* __restrict__ xt, float* __restrict__ sv) {
  const int row = blockIdx.x * 4 + (threadIdx.x >> 6);
  const int lane = threadIdx.x & 63;
  const unsigned short* p = xt + (long)row * 2048;
  float acc = 0.f;
#pragma unroll
  for (int i = 0; i < 4; ++i) {
    short8 v = *(const short8*)(p + (i * 64 + lane) * 8);
#pragma unroll
    for (int e = 0; e < 8; ++e) acc += bf2f((unsigned short)v[e]);
  }
#pragma unroll
  for (int off = 32; off; off >>= 1) acc += __shfl_down(acc, off);
  if (lane == 0) sv[row] = acc;
}

// out[z*768 + m] = sum_k A[z*a_bs + m*768 + k] * v[z*v_bs + k]
template<int ABF16>
__global__ __launch_bounds__(256) void gemv768(const void* __restrict__ Av,
                                               const float* __restrict__ v,
                                               float* __restrict__ out,
                                               long a_bs, long v_bs) {
  int z = blockIdx.y;
  int wid = threadIdx.x >> 6, lane = threadIdx.x & 63;
  for (int mi = 0; mi < 8; ++mi) {
    int m = blockIdx.x * 32 + wid * 8 + mi;
    float acc = 0.f;
    for (int k = lane; k < 768; k += 64) {
      float a = ABF16 ? bf2f(((const unsigned short*)Av)[z * a_bs + (long)m * 768 + k])
                      : ((const float*)Av)[z * a_bs + (long)m * 768 + k];
      acc += a * v[z * v_bs + k];
    }
#pragma unroll
    for (int off = 32; off; off >>= 1) acc += __shfl_down(acc, off);
    if (lane == 0) out[z * 768 + m] = acc;
  }
}

// C[m,n] = scale*sum_k A[m,k]*B[n,k] (+bias terms)  — 2-phase double-buffered
// BIAS_MODE: 0 none; 1: += bias[bz*bias_bs + col];
//            3: v += scale*(bias[row]*(b2[bz*768+col] + 2048*b4[col]) + b3[bz*768+row]*b4[col])
template<int BIAS_MODE, int OUT_BF16>
__global__ __launch_bounds__(256, 2)
void gemm_bt(const unsigned short* __restrict__ A,
             const unsigned short* __restrict__ B,
             const float* __restrict__ bias, const float* __restrict__ b2,
             const float* __restrict__ b3, const float* __restrict__ b4,
             void* __restrict__ Cv,
             int K, int lda, int ldb, int ldc,
             long a_bs, long b_bs, long c_bs, long bias_bs, float scale)
{
  __shared__ unsigned short As[2][BM * BK];
  __shared__ unsigned short Bs[2][BN * BK];

  const int tid  = threadIdx.x;
  const int wid  = tid >> 6;
  const int lane = tid & 63;
  const int bz   = blockIdx.z;
  const long bm  = (long)blockIdx.y * BM;
  const long bn  = (long)blockIdx.x * BN;

  const unsigned short* Ab = A + (long)bz * a_bs;
  const unsigned short* Bb = B + (long)bz * b_bs;

  f32x4 acc[4][4];
#pragma unroll
  for (int r = 0; r < 4; ++r)
#pragma unroll
    for (int c = 0; c < 4; ++c) acc[r][c] = (f32x4){0.f, 0.f, 0.f, 0.f};

  const int stg_row = lane >> 2;
  const int stg_k   = (lane & 3) * 8;
  const int fr = lane & 15;
  const int kf = (lane >> 4) * 8;

#define STAGE(p, k0) do { \
  _Pragma("unroll") \
  for (int i_ = 0; i_ < 2; ++i_) { \
    const int g_ = wid * 2 + i_; \
    const unsigned short* ga_ = Ab + (bm + g_ * 16 + stg_row) * (long)lda + (k0) + stg_k; \
    __builtin_amdgcn_global_load_lds((gmem_void*)ga_, (lds_void*)(&As[p][g_ * 16 * BK]), 16, 0, 0); \
    const unsigned short* gb_ = Bb + (bn + g_ * 16 + stg_row) * (long)ldb + (k0) + stg_k; \
    __builtin_amdgcn_global_load_lds((gmem_void*)gb_, (lds_void*)(&Bs[p][g_ * 16 * BK]), 16, 0, 0); \
  } } while (0)

  STAGE(0, 0);
  __syncthreads();

  const int nt = K / BK;
  for (int t = 0; t < nt; ++t) {
    const int p = t & 1;
    if (t + 1 < nt) STAGE(p ^ 1, (t + 1) * BK);   // prefetch overlaps compute

    short8 af[4], bfr[4];
#pragma unroll
    for (int r = 0; r < 4; ++r)
      af[r] = *(const short8*)(&As[p][((wid >> 1) * 64 + r * 16 + fr) * BK + kf]);
#pragma unroll
    for (int c = 0; c < 4; ++c)
      bfr[c] = *(const short8*)(&Bs[p][((wid & 1) * 64 + c * 16 + fr) * BK + kf]);
#pragma unroll
    for (int r = 0; r < 4; ++r)
#pragma unroll
      for (int c = 0; c < 4; ++c)
        acc[r][c] = __builtin_amdgcn_mfma_f32_16x16x32_bf16(af[r], bfr[c], acc[r][c], 0, 0, 0);

    __syncthreads();   // drains this iter's prefetch (vmcnt) + protects LDS reuse
  }
#undef STAGE

  const int wr  = (wid >> 1) * 64;
  const int wc  = (wid & 1) * 64;
  const int cr0 = (lane >> 4) * 4;
  const int cc  = lane & 15;

#pragma unroll
  for (int r = 0; r < 4; ++r)
#pragma unroll
    for (int c = 0; c < 4; ++c)
#pragma unroll
      for (int j = 0; j < 4; ++j) {
        long row = bm + wr + r * 16 + cr0 + j;
        long col = bn + wc + c * 16 + cc;
        float v = acc[r][c][j] * scale;
        if (BIAS_MODE == 1) v += bias[bz * bias_bs + col];
        else if (BIAS_MODE == 3)
          v += scale * (bias[row] * (b2[bz * 768 + col] + 2048.0f * b4[col])
                        + b3[bz * 768 + row] * b4[col]);
        long off = (long)bz * c_bs + row * (long)ldc + col;
        if (OUT_BF16) ((unsigned short*)Cv)[off] = f2bf(v);
        else          ((float*)Cv)[off] = v;
      }
}

extern "C" void kernel_launch(void* const* d_in, const int* in_sizes, int n_in,
                              void* d_out, int out_size, void* d_ws, size_t ws_size,
                              hipStream_t stream) {
  const float* x  = (const float*)d_in[0];
  const float* Wq = (const float*)d_in[1];
  const float* bq = (const float*)d_in[2];
  const float* Wk = (const float*)d_in[3];
  const float* bk = (const float*)d_in[4];
  const float* Wv = (const float*)d_in[5];
  const float* bv = (const float*)d_in[6];
  float* out = (float*)d_out;

  const int Bsz = 8, L = 2048, D = 768;
  const long xN = (long)Bsz * L * D;       // 12,582,912
  const long wN = (long)D * D;             // 589,824
  const long D2 = wN;

  char* ws = (char*)d_ws;
  unsigned short* xbuf = (unsigned short*)ws; ws += xN * 2;             // 25.2 MB: xt, then xb
  unsigned short* wkb  = (unsigned short*)ws; ws += wN * 2;
  unsigned short* wvb  = (unsigned short*)ws; ws += wN * 2;
  unsigned short* wqtb = (unsigned short*)ws; ws += wN * 2;             // Wq^T
  unsigned short* regA = (unsigned short*)ws; ws += (long)Bsz * D2 * 2; // 9.4 MB (G, then Mt)
  unsigned short* regB = (unsigned short*)ws; ws += (long)Bsz * D2 * 2; // 9.4 MB (N, then Pt)
  float* sv = (float*)ws; ws += (long)Bsz * D * 4;
  float* uv = (float*)ws; ws += (long)Bsz * D * 4;
  float* wvv = (float*)ws; ws += (long)Bsz * D * 4;
  float* rv = (float*)ws; ws += (long)Bsz * D * 4;   // total ~47.7 MB

  const float inv_sqrt_d = 0.036084391824351615f;  // 1/sqrt(768)
  dim3 blk(256);

  // xt[z][d][l] = bf16(x^T) into xbuf
  transpose_x<<<dim3(32, 24, 8), blk, 0, stream>>>(x, xbuf);
  cast_f32_bf16<<<(int)(wN / 8 / 256), blk, 0, stream>>>(Wk, wkb, (int)wN);
  cast_f32_bf16<<<(int)(wN / 8 / 256), blk, 0, stream>>>(Wv, wvb, (int)wN);
  transpose_cast<<<dim3(24, 24), blk, 0, stream>>>(Wq, wqtb, D, D);
  colsum_t<<<1536, blk, 0, stream>>>(xbuf, sv);

  // u = Wk s, w = Wv s (f32 weights, exact)
  gemv768<0><<<dim3(24, 8), blk, 0, stream>>>(Wk, sv, uv, 0, (long)D);
  gemv768<0><<<dim3(24, 8), blk, 0, stream>>>(Wv, sv, wvv, 0, (long)D);

  // G[z] = xt[z] · xt[z]^T  (K = L = 2048) -> regA
  gemm_bt<0, 1><<<dim3(6, 6, 8), blk, 0, stream>>>(
      xbuf, xbuf, nullptr, nullptr, nullptr, nullptr, regA,
      L, L, L, D, (long)D * L, (long)D * L, D2, 0, 1.0f);

  // xb[z][l][d] = bf16(x) — reuses xbuf (xt dead after G)
  cast_f32_bf16<<<(int)(xN / 8 / 256), blk, 0, stream>>>(x, xbuf, (int)xN);

  // N = Wv * G (G symmetric)  -> regB
  gemm_bt<0, 1><<<dim3(6, 6, 8), blk, 0, stream>>>(
      wvb, regA, nullptr, nullptr, nullptr, nullptr, regB,
      D, D, D, D, 0, D2, D2, 0, 1.0f);

  // Mt = (N * Wk^T + rank-1) * inv_sqrt_d  -> regA
  gemm_bt<3, 1><<<dim3(6, 6, 8), blk, 0, stream>>>(
      regB, wkb, bv, uv, wvv, bk, regA,
      D, D, D, D, D2, 0, D2, 0, inv_sqrt_d);

  // r[z][o] = sum_h Mt[z][o,h] * bq[h]
  gemv768<1><<<dim3(24, 8), blk, 0, stream>>>(regA, bq, rv, D2, 0);

  // Pt = Mt * Wqt^T  -> regB
  gemm_bt<0, 1><<<dim3(6, 6, 8), blk, 0, stream>>>(
      regA, wqtb, nullptr, nullptr, nullptr, nullptr, regB,
      D, D, D, D, D2, 0, D2, 0, 1.0f);

  // out[z][l,o] = sum_d xb[z,l,d] * Pt[z][o,d] + r[z][o]
  gemm_bt<1, 0><<<dim3(6, 16, 8), blk, 0, stream>>>(
      xbuf, regB, rv, nullptr, nullptr, nullptr, out,
      D, D, D, D, (long)L * D, D2, (long)L * D, (long)D, 1.0f);

  (void)in_sizes; (void)n_in; (void)out_size; (void)ws_size;
}

// Round 4
// 254.315 us; speedup vs baseline: 1.2951x; 1.0485x over previous
//
#include <hip/hip_runtime.h>
#include <hip/hip_bf16.h>
#include <stdint.h>

// out = (QK^T/sqrt(d))V = Q @ (K^T V)/sqrt(d)   (no softmax in ref)
// K^T V = Wk G Wv^T + (Wk s) bv^T + bk (Wv s)^T + L bk bv^T,  G = x^T x, s = colsum(x)
// out = x (Wq^T M) + 1 (bq^T M),  M = K^T V / sqrt(d)
// ws ~47.7 MB (known-safe). This round: depth-3 counted-vmcnt pipeline (T4)
// + XCD pinning z = bid&7 (T1) in all GEMMs.

#define BM 128
#define BN 128
#define BK 32

typedef __attribute__((ext_vector_type(8))) short short8;
typedef __attribute__((ext_vector_type(4))) float f32x4;
typedef __attribute__((address_space(3))) void lds_void;
typedef const __attribute__((address_space(1))) void gmem_void;

__device__ __forceinline__ unsigned short f2bf(float f) {
  union { float f; unsigned u; } v; v.f = f;
  unsigned r = v.u + 0x7fff + ((v.u >> 16) & 1);   // RNE
  return (unsigned short)(r >> 16);
}
__device__ __forceinline__ float bf2f(unsigned short u) {
  union { unsigned u; float f; } v; v.u = ((unsigned)u) << 16; return v.f;
}

__global__ __launch_bounds__(256) void cast_f32_bf16(
    const float* __restrict__ in, unsigned short* __restrict__ out, int n) {
  int i = (blockIdx.x * blockDim.x + threadIdx.x) * 8;
  if (i >= n) return;
  float4 v0 = *(const float4*)(in + i);
  float4 v1 = *(const float4*)(in + i + 4);
  unsigned short o[8];
  o[0] = f2bf(v0.x); o[1] = f2bf(v0.y); o[2] = f2bf(v0.z); o[3] = f2bf(v0.w);
  o[4] = f2bf(v1.x); o[5] = f2bf(v1.y); o[6] = f2bf(v1.z); o[7] = f2bf(v1.w);
  typedef __attribute__((ext_vector_type(8))) unsigned short ushort8;
  *(ushort8*)(out + i) = *(ushort8*)o;
}

// out[c*R + r] = bf16(in[r*C + c]);  R=C=768 (for Wq^T)
__global__ __launch_bounds__(256) void transpose_cast(
    const float* __restrict__ in, unsigned short* __restrict__ out, int R, int C) {
  __shared__ float tile[32][33];
  int r0 = blockIdx.y * 32, c0 = blockIdx.x * 32;
  int tx = threadIdx.x & 31, ty = threadIdx.x >> 5;
  for (int i = ty; i < 32; i += 8) tile[i][tx] = in[(long)(r0 + i) * C + c0 + tx];
  __syncthreads();
  for (int i = ty; i < 32; i += 8) out[(long)(c0 + i) * R + r0 + tx] = f2bf(tile[tx][i]);
}

// xt[z][d][l] = bf16(x[z][l][d]); tiles 64 l x 32 d. grid (32, 24, 8), block 256
__global__ __launch_bounds__(256) void transpose_x(
    const float* __restrict__ x, unsigned short* __restrict__ xt) {
  __shared__ float tile[64][33];
  const int z = blockIdx.z;
  const int l0 = blockIdx.x * 64, d0 = blockIdx.y * 32;
  const int tx = threadIdx.x & 31, ty = threadIdx.x >> 5;   // ty 0..7
  const float* xz = x + ((long)z * 2048 + l0) * 768 + d0;
#pragma unroll
  for (int i = 0; i < 8; ++i)
    tile[i * 8 + ty][tx] = xz[(long)(i * 8 + ty) * 768 + tx];
  __syncthreads();
  unsigned short* xtz = xt + ((long)z * 768 + d0) * 2048 + l0;
#pragma unroll
  for (int i = 0; i < 4; ++i) {
    int d = i * 8 + ty;
    ushort2 o;
    o.x = f2bf(tile[2 * tx][d]);
    o.y = f2bf(tile[2 * tx + 1][d]);
    *(ushort2*)(xtz + (long)d * 2048 + 2 * tx) = o;
  }
}

// sv[row] = sum_l xt[row][l], row = z*768+d. grid 1536, block 256 (4 rows/block)
__global__ __launch_bounds__(256) void colsum_t(
    const unsigned short* __restrict__ xt, float* __restrict__ sv) {
  const int row = blockIdx.x * 4 + (threadIdx.x >> 6);
  const int lane = threadIdx.x & 63;
  const unsigned short* p = xt + (long)row * 2048;
  float acc = 0.f;
#pragma unroll
  for (int i = 0; i < 4; ++i) {
    short8 v = *(const short8*)(p + (i * 64 + lane) * 8);
#pragma unroll
    for (int e = 0; e < 8; ++e) acc += bf2f((unsigned short)v[e]);
  }
#pragma unroll
  for (int off = 32; off; off >>= 1) acc += __shfl_down(acc, off);
  if (lane == 0) sv[row] = acc;
}

// out[z*768 + m] = sum_k A[z*a_bs + m*768 + k] * v[z*v_bs + k]
template<int ABF16>
__global__ __launch_bounds__(256) void gemv768(const void* __restrict__ Av,
                                               const float* __restrict__ v,
                                               float* __restrict__ out,
                                               long a_bs, long v_bs) {
  int z = blockIdx.y;
  int wid = threadIdx.x >> 6, lane = threadIdx.x & 63;
  for (int mi = 0; mi < 8; ++mi) {
    int m = blockIdx.x * 32 + wid * 8 + mi;
    float acc = 0.f;
    for (int k = lane; k < 768; k += 64) {
      float a = ABF16 ? bf2f(((const unsigned short*)Av)[z * a_bs + (long)m * 768 + k])
                      : ((const float*)Av)[z * a_bs + (long)m * 768 + k];
      acc += a * v[z * v_bs + k];
    }
#pragma unroll
    for (int off = 32; off; off >>= 1) acc += __shfl_down(acc, off);
    if (lane == 0) out[z * 768 + m] = acc;
  }
}

#define WAITV(n) asm volatile("s_waitcnt vmcnt(" #n ")" ::: "memory")

// C[m,n] = scale*sum_k A[m,k]*B[n,k] (+bias)  — depth-3 counted-vmcnt pipeline.
// 1-D grid, z = bid&7 (XCD pin), tile = bid>>3 -> (by, bx) via nbx.
// BIAS_MODE: 0 none; 1: += bias[bz*bias_bs + col];
//            3: v += scale*(bias[row]*(b2[..col] + 2048*b4[col]) + b3[..row]*b4[col])
template<int BIAS_MODE, int OUT_BF16>
__global__ __launch_bounds__(256, 2)
void gemm_bt(const unsigned short* __restrict__ A,
             const unsigned short* __restrict__ B,
             const float* __restrict__ bias, const float* __restrict__ b2,
             const float* __restrict__ b3, const float* __restrict__ b4,
             void* __restrict__ Cv,
             int K, int lda, int ldb, int ldc, int nbx,
             long a_bs, long b_bs, long c_bs, long bias_bs, float scale)
{
  __shared__ unsigned short As[4][BM * BK];
  __shared__ unsigned short Bs[4][BN * BK];

  const int tid  = threadIdx.x;
  const int wid  = tid >> 6;
  const int lane = tid & 63;
  const int bid  = blockIdx.x;
  const int bz   = bid & 7;            // batch == XCD
  const int tt   = bid >> 3;
  const long bm  = (long)(tt / nbx) * BM;
  const long bn  = (long)(tt % nbx) * BN;

  const unsigned short* Ab = A + (long)bz * a_bs;
  const unsigned short* Bb = B + (long)bz * b_bs;

  f32x4 acc[4][4];
#pragma unroll
  for (int r = 0; r < 4; ++r)
#pragma unroll
    for (int c = 0; c < 4; ++c) acc[r][c] = (f32x4){0.f, 0.f, 0.f, 0.f};

  const int stg_row = lane >> 2;
  const int stg_k   = (lane & 3) * 8;
  const int fr = lane & 15;
  const int kf = (lane >> 4) * 8;

#define STAGE(p, k0) do { \
  _Pragma("unroll") \
  for (int i_ = 0; i_ < 2; ++i_) { \
    const int g_ = wid * 2 + i_; \
    const unsigned short* ga_ = Ab + (bm + g_ * 16 + stg_row) * (long)lda + (k0) + stg_k; \
    __builtin_amdgcn_global_load_lds((gmem_void*)ga_, (lds_void*)(&As[p][g_ * 16 * BK]), 16, 0, 0); \
    const unsigned short* gb_ = Bb + (bn + g_ * 16 + stg_row) * (long)ldb + (k0) + stg_k; \
    __builtin_amdgcn_global_load_lds((gmem_void*)gb_, (lds_void*)(&Bs[p][g_ * 16 * BK]), 16, 0, 0); \
  } } while (0)

  const int nt = K / BK;       // >= 24 for all our GEMMs
  STAGE(0, 0);
  STAGE(1, BK);
  STAGE(2, 2 * BK);

  for (int t = 0; t < nt; ++t) {
    // counted waits: outstanding stages after wait = min(2, nt-1-t)
    if (t + 2 < nt)      WAITV(8);
    else if (t + 1 < nt) WAITV(4);
    else                 WAITV(0);
    __builtin_amdgcn_s_barrier();
    __builtin_amdgcn_sched_barrier(0);

    const int p = t & 3;
    short8 af[4], bfr[4];
#pragma unroll
    for (int r = 0; r < 4; ++r)
      af[r] = *(const short8*)(&As[p][((wid >> 1) * 64 + r * 16 + fr) * BK + kf]);
#pragma unroll
    for (int c = 0; c < 4; ++c)
      bfr[c] = *(const short8*)(&Bs[p][((wid & 1) * 64 + c * 16 + fr) * BK + kf]);
#pragma unroll
    for (int r = 0; r < 4; ++r)
#pragma unroll
      for (int c = 0; c < 4; ++c)
        acc[r][c] = __builtin_amdgcn_mfma_f32_16x16x32_bf16(af[r], bfr[c], acc[r][c], 0, 0, 0);

    if (t + 3 < nt) STAGE((t + 3) & 3, (t + 3) * BK);
  }
#undef STAGE

  const int wr  = (wid >> 1) * 64;
  const int wc  = (wid & 1) * 64;
  const int cr0 = (lane >> 4) * 4;
  const int cc  = lane & 15;

#pragma unroll
  for (int r = 0; r < 4; ++r)
#pragma unroll
    for (int c = 0; c < 4; ++c)
#pragma unroll
      for (int j = 0; j < 4; ++j) {
        long row = bm + wr + r * 16 + cr0 + j;
        long col = bn + wc + c * 16 + cc;
        float v = acc[r][c][j] * scale;
        if (BIAS_MODE == 1) v += bias[bz * bias_bs + col];
        else if (BIAS_MODE == 3)
          v += scale * (bias[row] * (b2[bz * 768 + col] + 2048.0f * b4[col])
                        + b3[bz * 768 + row] * b4[col]);
        long off = (long)bz * c_bs + row * (long)ldc + col;
        if (OUT_BF16) ((unsigned short*)Cv)[off] = f2bf(v);
        else          ((float*)Cv)[off] = v;
      }
}

extern "C" void kernel_launch(void* const* d_in, const int* in_sizes, int n_in,
                              void* d_out, int out_size, void* d_ws, size_t ws_size,
                              hipStream_t stream) {
  const float* x  = (const float*)d_in[0];
  const float* Wq = (const float*)d_in[1];
  const float* bq = (const float*)d_in[2];
  const float* Wk = (const float*)d_in[3];
  const float* bk = (const float*)d_in[4];
  const float* Wv = (const float*)d_in[5];
  const float* bv = (const float*)d_in[6];
  float* out = (float*)d_out;

  const int Bsz = 8, L = 2048, D = 768;
  const long xN = (long)Bsz * L * D;       // 12,582,912
  const long wN = (long)D * D;             // 589,824
  const long D2 = wN;

  char* ws = (char*)d_ws;
  unsigned short* xbuf = (unsigned short*)ws; ws += xN * 2;             // 25.2 MB: xt, then xb
  unsigned short* wkb  = (unsigned short*)ws; ws += wN * 2;
  unsigned short* wvb  = (unsigned short*)ws; ws += wN * 2;
  unsigned short* wqtb = (unsigned short*)ws; ws += wN * 2;             // Wq^T
  unsigned short* regA = (unsigned short*)ws; ws += (long)Bsz * D2 * 2; // 9.4 MB (G, then Mt)
  unsigned short* regB = (unsigned short*)ws; ws += (long)Bsz * D2 * 2; // 9.4 MB (N, then Pt)
  float* sv = (float*)ws; ws += (long)Bsz * D * 4;
  float* uv = (float*)ws; ws += (long)Bsz * D * 4;
  float* wvv = (float*)ws; ws += (long)Bsz * D * 4;
  float* rv = (float*)ws; ws += (long)Bsz * D * 4;   // total ~47.7 MB

  const float inv_sqrt_d = 0.036084391824351615f;  // 1/sqrt(768)
  dim3 blk(256);

  // xt[z][d][l] = bf16(x^T) into xbuf
  transpose_x<<<dim3(32, 24, 8), blk, 0, stream>>>(x, xbuf);
  cast_f32_bf16<<<(int)(wN / 8 / 256), blk, 0, stream>>>(Wk, wkb, (int)wN);
  cast_f32_bf16<<<(int)(wN / 8 / 256), blk, 0, stream>>>(Wv, wvb, (int)wN);
  transpose_cast<<<dim3(24, 24), blk, 0, stream>>>(Wq, wqtb, D, D);
  colsum_t<<<1536, blk, 0, stream>>>(xbuf, sv);

  // u = Wk s, w = Wv s (f32 weights, exact)
  gemv768<0><<<dim3(24, 8), blk, 0, stream>>>(Wk, sv, uv, 0, (long)D);
  gemv768<0><<<dim3(24, 8), blk, 0, stream>>>(Wv, sv, wvv, 0, (long)D);

  // G[z] = xt[z] · xt[z]^T  (K = L = 2048) -> regA
  gemm_bt<0, 1><<<dim3(288), blk, 0, stream>>>(
      xbuf, xbuf, nullptr, nullptr, nullptr, nullptr, regA,
      L, L, L, D, 6, (long)D * L, (long)D * L, D2, 0, 1.0f);

  // xb[z][l][d] = bf16(x) — reuses xbuf (xt dead after G)
  cast_f32_bf16<<<(int)(xN / 8 / 256), blk, 0, stream>>>(x, xbuf, (int)xN);

  // N = Wv * G (G symmetric)  -> regB
  gemm_bt<0, 1><<<dim3(288), blk, 0, stream>>>(
      wvb, regA, nullptr, nullptr, nullptr, nullptr, regB,
      D, D, D, D, 6, 0, D2, D2, 0, 1.0f);

  // Mt = (N * Wk^T + rank-1) * inv_sqrt_d  -> regA
  gemm_bt<3, 1><<<dim3(288), blk, 0, stream>>>(
      regB, wkb, bv, uv, wvv, bk, regA,
      D, D, D, D, 6, D2, 0, D2, 0, inv_sqrt_d);

  // r[z][o] = sum_h Mt[z][o,h] * bq[h]
  gemv768<1><<<dim3(24, 8), blk, 0, stream>>>(regA, bq, rv, D2, 0);

  // Pt = Mt * Wqt^T  -> regB
  gemm_bt<0, 1><<<dim3(288), blk, 0, stream>>>(
      regA, wqtb, nullptr, nullptr, nullptr, nullptr, regB,
      D, D, D, D, 6, D2, 0, D2, 0, 1.0f);

  // out[z][l,o] = sum_d xb[z,l,d] * Pt[z][o,d] + r[z][o]
  gemm_bt<1, 0><<<dim3(768), blk, 0, stream>>>(
      xbuf, regB, rv, nullptr, nullptr, nullptr, out,
      D, D, D, D, 6, (long)L * D, D2, (long)L * D, (long)D, 1.0f);

  (void)in_sizes; (void)n_in; (void)out_size; (void)ws_size;
}